// Round 1
// baseline (499.252 us; speedup 1.0000x reference)
//
#include <hip/hip_runtime.h>
#include <hip/hip_bf16.h>
#include <math.h>

#define B_ 2
#define S_ 2048
#define D_ 1024
#define H_ 16
#define DH_ 64
#define DFF_ 4096
#define M_ (B_*S_)

typedef __bf16 bf16;
typedef __bf16 bf16x8 __attribute__((ext_vector_type(8)));
typedef __bf16 bf16x4 __attribute__((ext_vector_type(4)));
typedef float f32x4 __attribute__((ext_vector_type(4)));

// ---------------- RMSNorm: fp32 [rows, D] -> bf16 ----------------
__global__ __launch_bounds__(256) void rmsnorm_kernel(const float* __restrict__ x,
    const float* __restrict__ scale, bf16* __restrict__ out) {
  __shared__ float red[4];
  int row = blockIdx.x, t = threadIdx.x;
  const float4* xr = (const float4*)(x + (size_t)row * D_);
  float4 v = xr[t];
  float ss = v.x*v.x + v.y*v.y + v.z*v.z + v.w*v.w;
  #pragma unroll
  for (int off = 32; off > 0; off >>= 1) ss += __shfl_down(ss, off, 64);
  if ((t & 63) == 0) red[t >> 6] = ss;
  __syncthreads();
  float tot = red[0] + red[1] + red[2] + red[3];
  float r = rsqrtf(tot * (1.0f / D_) + 1e-8f);
  float4 sc = ((const float4*)scale)[t];
  bf16x4 o;
  o[0] = (bf16)(v.x * sc.x * r);
  o[1] = (bf16)(v.y * sc.y * r);
  o[2] = (bf16)(v.z * sc.z * r);
  o[3] = (bf16)(v.w * sc.w * r);
  *(bf16x4*)(out + (size_t)row * D_ + t * 4) = o;
}

// ---------------- Weight transpose: fp32 [K,N] -> bf16 [N,K] ----------------
__global__ __launch_bounds__(256) void wtrans_kernel(const float* __restrict__ W,
    bf16* __restrict__ Wt, int K, int N) {
  __shared__ float tile[32][33];
  int n0 = blockIdx.x * 32, k0 = blockIdx.y * 32;
  int tx = threadIdx.x & 31, ty = threadIdx.x >> 5;
  #pragma unroll
  for (int i = 0; i < 4; i++)
    tile[ty + i*8][tx] = W[(size_t)(k0 + ty + i*8) * N + n0 + tx];
  __syncthreads();
  #pragma unroll
  for (int i = 0; i < 4; i++)
    Wt[(size_t)(n0 + ty + i*8) * K + k0 + tx] = (bf16)tile[tx][ty + i*8];
}

// ---------------- V transpose: bf16 [B*H][S,DH] -> [B*H][DH,S] ----------------
__global__ __launch_bounds__(256) void vtrans_kernel(const bf16* __restrict__ Vin,
    bf16* __restrict__ Vt) {
  __shared__ bf16 tile[32][34];
  size_t base = (size_t)blockIdx.z * (S_ * DH_);
  int s0 = blockIdx.x * 32, d0 = blockIdx.y * 32;
  int tx = threadIdx.x & 31, ty = threadIdx.x >> 5;
  #pragma unroll
  for (int i = 0; i < 4; i++)
    tile[ty + i*8][tx] = Vin[base + (size_t)(s0 + ty + i*8) * DH_ + d0 + tx];
  __syncthreads();
  #pragma unroll
  for (int i = 0; i < 4; i++)
    Vt[base + (size_t)(d0 + ty + i*8) * S_ + s0 + tx] = tile[tx][ty + i*8];
}

__device__ __forceinline__ float gelu_exact(float v) {
  return 0.5f * v * (1.0f + erff(v * 0.70710678118654752f));
}

// ---------------- GEMM: C[M,N] = A[M,K](bf16) @ Bt[N,K]^T + bias, epilogue ----------------
// MODE 0: qkv scatter to [3][B,H,S,DH] bf16
// MODE 1: fp32 out = acc + bias + res   (out-proj + residual)
// MODE 2: bf16 out = gelu(acc + bias)   (ffn1)
// MODE 3: fp32 out = acc + bias + res   (ffn2 + residual -> d_out)
template<int MODE>
__global__ __launch_bounds__(256) void gemm_kernel(
    const bf16* __restrict__ A, const bf16* __restrict__ Bt,
    const float* __restrict__ bias, const float* __restrict__ res,
    void* __restrict__ outp, int M, int N, int K) {
  __shared__ __align__(16) bf16 As[128 * 32];
  __shared__ __align__(16) bf16 Bs[128 * 32];
  int t = threadIdx.x;
  int wave = t >> 6, lane = t & 63;
  int lm = lane & 15, lg = lane >> 4;
  int m0 = blockIdx.y * 128, n0 = blockIdx.x * 128;
  int wm = (wave >> 1) * 64, wn = (wave & 1) * 64;
  f32x4 acc[4][4] = {};

  const bf16* Ag = A + (size_t)(m0 + (t >> 2)) * K + (t & 3) * 8;
  const bf16* Bg = Bt + (size_t)(n0 + (t >> 2)) * K + (t & 3) * 8;

  for (int k0 = 0; k0 < K; k0 += 32) {
    uint4 a0 = *(const uint4*)(Ag + k0);
    uint4 a1 = *(const uint4*)(Ag + k0 + (size_t)64 * K);
    uint4 b0 = *(const uint4*)(Bg + k0);
    uint4 b1 = *(const uint4*)(Bg + k0 + (size_t)64 * K);
    __syncthreads();
    *(uint4*)(As + t * 8) = a0;
    *(uint4*)(As + 2048 + t * 8) = a1;
    *(uint4*)(Bs + t * 8) = b0;
    *(uint4*)(Bs + 2048 + t * 8) = b1;
    __syncthreads();
    bf16x8 af[4], bfr[4];
    #pragma unroll
    for (int i = 0; i < 4; i++)
      af[i] = *(const bf16x8*)(As + (wm + i * 16 + lm) * 32 + lg * 8);
    #pragma unroll
    for (int j = 0; j < 4; j++)
      bfr[j] = *(const bf16x8*)(Bs + (wn + j * 16 + lm) * 32 + lg * 8);
    #pragma unroll
    for (int i = 0; i < 4; i++)
      #pragma unroll
      for (int j = 0; j < 4; j++)
        acc[i][j] = __builtin_amdgcn_mfma_f32_16x16x32_bf16(af[i], bfr[j], acc[i][j], 0, 0, 0);
  }

  #pragma unroll
  for (int i = 0; i < 4; i++) {
    int row = m0 + wm + i * 16 + lg * 4;
    #pragma unroll
    for (int j = 0; j < 4; j++) {
      int col = n0 + wn + j * 16 + lm;
      float bcol = bias[col];
      #pragma unroll
      for (int r = 0; r < 4; r++) {
        float v = acc[i][j][r] + bcol;
        int rr = row + r;
        if (MODE == 0) {
          int which = col >> 10, d = col & 1023;
          int hh = d >> 6, dh = d & 63;
          int bb = rr >> 11, s = rr & 2047;
          ((bf16*)outp)[(size_t)which * ((size_t)B_*H_*S_*DH_) +
              ((size_t)(bb * H_ + hh) * S_ + s) * DH_ + dh] = (bf16)v;
        } else if (MODE == 1) {
          ((float*)outp)[(size_t)rr * N + col] = v + res[(size_t)rr * N + col];
        } else if (MODE == 2) {
          ((bf16*)outp)[(size_t)rr * N + col] = (bf16)gelu_exact(v);
        } else {
          ((float*)outp)[(size_t)rr * N + col] = v + res[(size_t)rr * N + col];
        }
      }
    }
  }
}

// ---------------- Flash attention: q,k [B,H,S,DH], vT [B,H,DH,S] -> ao [B,S,D] bf16 ----------------
__global__ __launch_bounds__(256) void attn_kernel(
    const bf16* __restrict__ q, const bf16* __restrict__ k,
    const bf16* __restrict__ vT, bf16* __restrict__ ao) {
  __shared__ __align__(16) bf16 Qs[64 * 72];
  __shared__ __align__(16) bf16 Ks[64 * 72];
  __shared__ __align__(16) bf16 Vs[64 * 72];   // [dh][kv]
  __shared__ __align__(16) bf16 Ps[4 * 16 * 72];
  int t = threadIdx.x, wave = t >> 6, lane = t & 63;
  int lm = lane & 15, lg = lane >> 4;
  int q0 = blockIdx.x * 64;
  int h = blockIdx.y, b = blockIdx.z;
  size_t base = (size_t)(b * H_ + h) * ((size_t)S_ * DH_);
  const bf16* Q = q + base;
  const bf16* K = k + base;
  const bf16* V = vT + base;   // [DH][S]
  float slope = exp2f(-0.5f * (float)(h + 1));

  #pragma unroll
  for (int it = 0; it < 2; it++) {
    int c = t + it * 256;
    int row = c >> 3, col = (c & 7) * 8;
    *(uint4*)(Qs + row * 72 + col) = *(const uint4*)(Q + (size_t)(q0 + row) * DH_ + col);
  }

  f32x4 oacc[4] = {};
  float mrun[4], lrun[4];
  #pragma unroll
  for (int r = 0; r < 4; r++) { mrun[r] = -INFINITY; lrun[r] = 0.f; }

  for (int j0 = 0; j0 < S_; j0 += 64) {
    __syncthreads();   // protect Ks/Vs from prior iteration's readers
    #pragma unroll
    for (int it = 0; it < 2; it++) {
      int c = t + it * 256;
      int row = c >> 3, col = (c & 7) * 8;
      *(uint4*)(Ks + row * 72 + col) = *(const uint4*)(K + (size_t)(j0 + row) * DH_ + col);
      *(uint4*)(Vs + row * 72 + col) = *(const uint4*)(V + (size_t)row * S_ + j0 + col);
    }
    __syncthreads();

    const bf16x8 aq0 = *(const bf16x8*)(Qs + (wave * 16 + lm) * 72 + lg * 8);
    const bf16x8 aq1 = *(const bf16x8*)(Qs + (wave * 16 + lm) * 72 + 32 + lg * 8);
    f32x4 sc[4];
    #pragma unroll
    for (int tt = 0; tt < 4; tt++) {
      f32x4 a = {};
      bf16x8 kb0 = *(const bf16x8*)(Ks + (tt * 16 + lm) * 72 + lg * 8);
      bf16x8 kb1 = *(const bf16x8*)(Ks + (tt * 16 + lm) * 72 + 32 + lg * 8);
      a = __builtin_amdgcn_mfma_f32_16x16x32_bf16(aq0, kb0, a, 0, 0, 0);
      a = __builtin_amdgcn_mfma_f32_16x16x32_bf16(aq1, kb1, a, 0, 0, 0);
      sc[tt] = a;
    }
    float mx[4] = {-INFINITY, -INFINITY, -INFINITY, -INFINITY};
    #pragma unroll
    for (int tt = 0; tt < 4; tt++)
      #pragma unroll
      for (int r = 0; r < 4; r++) {
        float iq = (float)(q0 + wave * 16 + lg * 4 + r);
        float jk = (float)(j0 + tt * 16 + lm);
        float s = sc[tt][r] * 0.125f - slope * fabsf(iq - jk);
        sc[tt][r] = s;
        mx[r] = fmaxf(mx[r], s);
      }
    #pragma unroll
    for (int r = 0; r < 4; r++) {
      #pragma unroll
      for (int off = 1; off < 16; off <<= 1)
        mx[r] = fmaxf(mx[r], __shfl_xor(mx[r], off, 16));
    }
    float al[4], rs[4] = {0.f, 0.f, 0.f, 0.f};
    #pragma unroll
    for (int r = 0; r < 4; r++) {
      float mn = fmaxf(mrun[r], mx[r]);
      al[r] = __expf(mrun[r] - mn);
      mrun[r] = mn;
    }
    bf16* Pw = Ps + wave * (16 * 72);
    #pragma unroll
    for (int tt = 0; tt < 4; tt++)
      #pragma unroll
      for (int r = 0; r < 4; r++) {
        float p = __expf(sc[tt][r] - mrun[r]);
        rs[r] += p;
        Pw[(lg * 4 + r) * 72 + tt * 16 + lm] = (bf16)p;
      }
    #pragma unroll
    for (int r = 0; r < 4; r++) {
      #pragma unroll
      for (int off = 1; off < 16; off <<= 1)
        rs[r] += __shfl_xor(rs[r], off, 16);
      lrun[r] = lrun[r] * al[r] + rs[r];
    }
    #pragma unroll
    for (int tt = 0; tt < 4; tt++)
      #pragma unroll
      for (int r = 0; r < 4; r++)
        oacc[tt][r] *= al[r];

    bf16x8 ap0 = *(const bf16x8*)(Pw + lm * 72 + lg * 8);
    bf16x8 ap1 = *(const bf16x8*)(Pw + lm * 72 + 32 + lg * 8);
    #pragma unroll
    for (int tt = 0; tt < 4; tt++) {
      bf16x8 vb0 = *(const bf16x8*)(Vs + (tt * 16 + lm) * 72 + lg * 8);
      bf16x8 vb1 = *(const bf16x8*)(Vs + (tt * 16 + lm) * 72 + 32 + lg * 8);
      oacc[tt] = __builtin_amdgcn_mfma_f32_16x16x32_bf16(ap0, vb0, oacc[tt], 0, 0, 0);
      oacc[tt] = __builtin_amdgcn_mfma_f32_16x16x32_bf16(ap1, vb1, oacc[tt], 0, 0, 0);
    }
  }

  #pragma unroll
  for (int tt = 0; tt < 4; tt++)
    #pragma unroll
    for (int r = 0; r < 4; r++) {
      int row = q0 + wave * 16 + lg * 4 + r;
      int col = h * 64 + tt * 16 + lm;
      ao[((size_t)(b * S_) + row) * D_ + col] = (bf16)(oacc[tt][r] / lrun[r]);
    }
}

extern "C" void kernel_launch(void* const* d_in, const int* in_sizes, int n_in,
                              void* d_out, int out_size, void* d_ws, size_t ws_size,
                              hipStream_t stream) {
  const float* x      = (const float*)d_in[0];
  const float* scale1 = (const float*)d_in[1];
  const float* scale2 = (const float*)d_in[2];
  const float* w_qkv  = (const float*)d_in[3];
  const float* b_qkv  = (const float*)d_in[4];
  const float* w_out  = (const float*)d_in[5];
  const float* b_out  = (const float*)d_in[6];
  const float* w1     = (const float*)d_in[7];
  const float* b1     = (const float*)d_in[8];
  const float* w2     = (const float*)d_in[9];
  const float* b2     = (const float*)d_in[10];

  char* ws = (char*)d_ws;
  const size_t MB = 1024 * 1024;
  // layout (total 80 MB):
  bf16* xn    = (bf16*)(ws + 0);        // 8MB [M,D]; reused as ao after qkv gemm
  bf16* qb    = (bf16*)(ws + 8*MB);     // 8MB q [B,H,S,DH]; reused as xn2 after attn
  bf16* kb    = (bf16*)(ws + 16*MB);    // 8MB k
  bf16* vb    = (bf16*)(ws + 24*MB);    // 8MB v
  bf16* vT    = (bf16*)(ws + 32*MB);    // 8MB v transposed [B,H,DH,S]
  bf16* wqkvT = (bf16*)(ws + 40*MB);    // 6MB
  bf16* woutT = (bf16*)(ws + 46*MB);    // 2MB
  bf16* w1T   = (bf16*)(ws + 48*MB);    // 8MB
  bf16* w2T   = (bf16*)(ws + 56*MB);    // 8MB
  float* x2   = (float*)(ws + 64*MB);   // 16MB fp32 [M,D]
  bf16* xn2   = qb;                     // reuse (q dead after attention)
  bf16* hbuf  = (bf16*)(ws + 16*MB);    // 32MB [M,DFF]; reuses k,v,vT,wqkvT,woutT (all dead)
  bf16* ao    = xn;

  dim3 blk(256);
  wtrans_kernel<<<dim3(3072/32, 1024/32), blk, 0, stream>>>(w_qkv, wqkvT, 1024, 3072);
  wtrans_kernel<<<dim3(1024/32, 1024/32), blk, 0, stream>>>(w_out, woutT, 1024, 1024);
  wtrans_kernel<<<dim3(4096/32, 1024/32), blk, 0, stream>>>(w1, w1T, 1024, 4096);
  wtrans_kernel<<<dim3(1024/32, 4096/32), blk, 0, stream>>>(w2, w2T, 4096, 1024);

  rmsnorm_kernel<<<dim3(M_), blk, 0, stream>>>(x, scale1, xn);

  gemm_kernel<0><<<dim3(3072/128, M_/128), blk, 0, stream>>>(
      xn, wqkvT, b_qkv, nullptr, qb, M_, 3072, 1024);

  vtrans_kernel<<<dim3(S_/32, DH_/32, B_*H_), blk, 0, stream>>>(vb, vT);

  attn_kernel<<<dim3(S_/64, H_, B_), blk, 0, stream>>>(qb, kb, vT, ao);

  gemm_kernel<1><<<dim3(1024/128, M_/128), blk, 0, stream>>>(
      ao, woutT, b_out, x, x2, M_, 1024, 1024);

  rmsnorm_kernel<<<dim3(M_), blk, 0, stream>>>(x2, scale2, xn2);

  gemm_kernel<2><<<dim3(4096/128, M_/128), blk, 0, stream>>>(
      xn2, w1T, b1, nullptr, hbuf, M_, 4096, 1024);

  gemm_kernel<3><<<dim3(1024/128, M_/128), blk, 0, stream>>>(
      hbuf, w2T, b2, x2, d_out, M_, 1024, 4096);
}